// Round 5
// baseline (80.839 us; speedup 1.0000x reference)
//
#include <hip/hip_runtime.h>

// Geometric product in Cl(3,0), blades short-lex ordered:
// idx: 0=1, 1=e1, 2=e2, 3=e3, 4=e12, 5=e13, 6=e23, 7=e123
// Hardcoded 64-term signed table (METRIC=[1,1,1] fixed in setup_inputs).
//
// Round 5: persistent grid-stride kernel. 2048 blocks x 256 threads, each
// thread handles 8 multivectors with unroll-4 so ~8-16 global_load_dwordx4
// are in flight per thread (MLP), and block-dispatch overhead drops 16x.
// Round-1 compute body (mv-per-thread, no shuffles): round 4 showed the
// stride-32B float4-pair pattern is NOT a limiter, and it needs no VALU
// shuffle traffic.
// Round-3 lesson: NT stores bypass L3 write-back -> +55% write traffic. No.

typedef float v4f __attribute__((ext_vector_type(4)));

__global__ __launch_bounds__(256) void clifford_gp_kernel(
    const v4f* __restrict__ a4, const v4f* __restrict__ b4,
    v4f* __restrict__ o4, int n_mv)
{
    int stride = gridDim.x * blockDim.x;
    #pragma unroll 4
    for (int t = blockIdx.x * blockDim.x + threadIdx.x; t < n_mv; t += stride) {
        v4f alo = a4[2 * t], ahi = a4[2 * t + 1];
        v4f blo = b4[2 * t], bhi = b4[2 * t + 1];

        float a0 = alo.x, a1 = alo.y, a2 = alo.z, a3 = alo.w;
        float A4 = ahi.x, a5 = ahi.y, a6 = ahi.z, a7 = ahi.w;
        float b0 = blo.x, b1 = blo.y, b2 = blo.z, b3 = blo.w;
        float B4 = bhi.x, b5 = bhi.y, b6 = bhi.z, b7 = bhi.w;

        v4f olo, ohi;
        // scalar
        olo.x = a0*b0 + a1*b1 + a2*b2 + a3*b3 - A4*B4 - a5*b5 - a6*b6 - a7*b7;
        // e1
        olo.y = a0*b1 + a1*b0 - a2*B4 + A4*b2 - a3*b5 + a5*b3 - a6*b7 - a7*b6;
        // e2
        olo.z = a0*b2 + a2*b0 + a1*B4 - A4*b1 - a3*b6 + a6*b3 + a5*b7 + a7*b5;
        // e3
        olo.w = a0*b3 + a3*b0 + a1*b5 - a5*b1 + a2*b6 - a6*b2 - A4*b7 - a7*B4;
        // e12
        ohi.x = a0*B4 + A4*b0 + a1*b2 - a2*b1 + a3*b7 + a7*b3 - a5*b6 + a6*b5;
        // e13
        ohi.y = a0*b5 + a5*b0 + a1*b3 - a3*b1 - a2*b7 - a7*b2 + A4*b6 - a6*B4;
        // e23
        ohi.z = a0*b6 + a6*b0 + a2*b3 - a3*b2 + a1*b7 + a7*b1 - A4*b5 + a5*B4;
        // e123
        ohi.w = a0*b7 + a7*b0 + a1*b6 + a6*b1 - a2*b5 - a5*b2 + a3*B4 + A4*b3;

        o4[2 * t]     = olo;
        o4[2 * t + 1] = ohi;
    }
}

extern "C" void kernel_launch(void* const* d_in, const int* in_sizes, int n_in,
                              void* d_out, int out_size, void* d_ws, size_t ws_size,
                              hipStream_t stream) {
    const v4f* a = (const v4f*)d_in[0];
    const v4f* b = (const v4f*)d_in[1];
    v4f* out = (v4f*)d_out;
    int n_mv = in_sizes[0] / 8;  // 65536*64 = 4,194,304 multivectors
    int block = 256;
    int grid = 2048;  // persistent: 8 mv/thread grid-stride
    clifford_gp_kernel<<<grid, block, 0, stream>>>(a, b, out, n_mv);
}

// Round 6
// 74.193 us; speedup vs baseline: 1.0896x; 1.0896x over previous
//
#include <hip/hip_runtime.h>

// Geometric product in Cl(3,0), blades short-lex ordered:
// idx: 0=1, 1=e1, 2=e2, 3=e3, 4=e12, 5=e13, 6=e23, 7=e123
// Hardcoded 64-term signed table (METRIC=[1,1,1] fixed in setup_inputs).
//
// FINAL (revert to round-1 best, 72.9-73.4 us):
// 1 thread = 1 multivector: 2x float4 loads per input, 64 FMA in regs,
// 2x float4 stores. Exact grid (16384 blocks), no LDS, no shuffles.
// Ablation history:
//   r3 NT stores:        -40% (bypasses L3 write-back, +55% write traffic)
//   r4 stride-1 shuffle:  neutral (coalescing was not the limiter)
//   r5 persistent grid:  -10% (occupancy 77->60, worse locality)
// Counters at best: FETCH 131MB + WRITE 131MB at HBM, 134MB reads L3-hit,
// 402MB logical / 73us = 5.5 TB/s = 87% of 2-stream copy ceiling with a
// 3-stream (2r+1w) pattern -> practical memory roofline.

typedef float v4f __attribute__((ext_vector_type(4)));

__global__ __launch_bounds__(256) void clifford_gp_kernel(
    const v4f* __restrict__ a4, const v4f* __restrict__ b4,
    v4f* __restrict__ o4, int n_mv)
{
    int t = blockIdx.x * blockDim.x + threadIdx.x;
    if (t >= n_mv) return;

    v4f alo = a4[2 * t], ahi = a4[2 * t + 1];
    v4f blo = b4[2 * t], bhi = b4[2 * t + 1];

    float a0 = alo.x, a1 = alo.y, a2 = alo.z, a3 = alo.w;
    float A4 = ahi.x, a5 = ahi.y, a6 = ahi.z, a7 = ahi.w;
    float b0 = blo.x, b1 = blo.y, b2 = blo.z, b3 = blo.w;
    float B4 = bhi.x, b5 = bhi.y, b6 = bhi.z, b7 = bhi.w;

    v4f olo, ohi;
    // scalar
    olo.x = a0*b0 + a1*b1 + a2*b2 + a3*b3 - A4*B4 - a5*b5 - a6*b6 - a7*b7;
    // e1
    olo.y = a0*b1 + a1*b0 - a2*B4 + A4*b2 - a3*b5 + a5*b3 - a6*b7 - a7*b6;
    // e2
    olo.z = a0*b2 + a2*b0 + a1*B4 - A4*b1 - a3*b6 + a6*b3 + a5*b7 + a7*b5;
    // e3
    olo.w = a0*b3 + a3*b0 + a1*b5 - a5*b1 + a2*b6 - a6*b2 - A4*b7 - a7*B4;
    // e12
    ohi.x = a0*B4 + A4*b0 + a1*b2 - a2*b1 + a3*b7 + a7*b3 - a5*b6 + a6*b5;
    // e13
    ohi.y = a0*b5 + a5*b0 + a1*b3 - a3*b1 - a2*b7 - a7*b2 + A4*b6 - a6*B4;
    // e23
    ohi.z = a0*b6 + a6*b0 + a2*b3 - a3*b2 + a1*b7 + a7*b1 - A4*b5 + a5*B4;
    // e123
    ohi.w = a0*b7 + a7*b0 + a1*b6 + a6*b1 - a2*b5 - a5*b2 + a3*B4 + A4*b3;

    o4[2 * t]     = olo;
    o4[2 * t + 1] = ohi;
}

extern "C" void kernel_launch(void* const* d_in, const int* in_sizes, int n_in,
                              void* d_out, int out_size, void* d_ws, size_t ws_size,
                              hipStream_t stream) {
    const v4f* a = (const v4f*)d_in[0];
    const v4f* b = (const v4f*)d_in[1];
    v4f* out = (v4f*)d_out;
    int n_mv = in_sizes[0] / 8;  // 65536*64 = 4,194,304 multivectors
    int block = 256;
    int grid = (n_mv + block - 1) / block;
    clifford_gp_kernel<<<grid, block, 0, stream>>>(a, b, out, n_mv);
}